// Round 1
// baseline (562.618 us; speedup 1.0000x reference)
//
#include <hip/hip_runtime.h>

// ---------------------------------------------------------------------------
// QuantLinear: out = fq_act(x, g=128) @ fq_wgt(w)^T + bias
//   x: [M=8192, K=4096] fp32, w: [N=4096, K=4096] fp32, bias: [N] fp32
// Pipeline: quantize x->bf16 (ws), w->bf16 (ws), then bf16 MFMA GEMM (m97
// structure: 128x128 tile, BK=32, global_load_lds width=16, fused bias).
// ---------------------------------------------------------------------------

typedef __attribute__((ext_vector_type(8))) short bf16x8;
typedef __attribute__((ext_vector_type(8))) short s8v;
typedef __attribute__((ext_vector_type(4))) float f32x4;

// float -> bf16 round-to-nearest-even (manual, avoids hip_bf16 API variance)
static __device__ __forceinline__ unsigned short f2bf(float f) {
    unsigned int u = __builtin_bit_cast(unsigned int, f);
    u = (u + 0x7fffu + ((u >> 16) & 1u)) >> 16;
    return (unsigned short)u;
}

static __device__ __forceinline__ float fq(float v, float scale) {
    // matches jnp: clip(round(v/scale), -128, 127) * scale ; rintf = half-even
    float q = rintf(v / scale);
    q = fminf(fmaxf(q, -128.0f), 127.0f);
    return q * scale;
}

static __device__ __forceinline__ void load_lds16(const short* g, short* l) {
    __builtin_amdgcn_global_load_lds(
        (const __attribute__((address_space(1))) void*)g,
        (__attribute__((address_space(3))) void*)l, 16, 0, 0);
}

// --------------------- activation quant: per-group-128 ---------------------
// one block (256 thr) per token row; thread handles 16 contiguous elems, so a
// group of 128 = 8 consecutive lanes -> shfl_xor(1,2,4) reduce.
__global__ __launch_bounds__(256) void act_quant_kernel(
        const float* __restrict__ x, short* __restrict__ xq, int in_f) {
    const int row = blockIdx.x, t = threadIdx.x;
    const float* xr = x + (size_t)row * in_f;
    short* xo = xq + (size_t)row * in_f;
    for (int base = t * 16; base < in_f; base += 256 * 16) {
        float v[16];
#pragma unroll
        for (int j = 0; j < 4; j++) {
            float4 f = *(const float4*)(xr + base + j * 4);
            v[j * 4 + 0] = f.x; v[j * 4 + 1] = f.y;
            v[j * 4 + 2] = f.z; v[j * 4 + 3] = f.w;
        }
        float m = 0.0f;
#pragma unroll
        for (int j = 0; j < 16; j++) m = fmaxf(m, fabsf(v[j]));
        m = fmaxf(m, __shfl_xor(m, 1));
        m = fmaxf(m, __shfl_xor(m, 2));
        m = fmaxf(m, __shfl_xor(m, 4));
        const float scale = fmaxf(m / 127.0f, 1e-8f);
        short o[16];
#pragma unroll
        for (int j = 0; j < 16; j++) o[j] = (short)f2bf(fq(v[j], scale));
        s8v s0, s1;
#pragma unroll
        for (int j = 0; j < 8; j++) { s0[j] = o[j]; s1[j] = o[8 + j]; }
        *(s8v*)(xo + base) = s0;
        *(s8v*)(xo + base + 8) = s1;
    }
}

// --------------------- weight quant: per-row ---------------------
__global__ __launch_bounds__(256) void wgt_quant_kernel(
        const float* __restrict__ w, short* __restrict__ wq, int K) {
    const int row = blockIdx.x, t = threadIdx.x;
    const float* wr = w + (size_t)row * K;
    short* wo = wq + (size_t)row * K;
    float m = 0.0f;
    for (int i = t * 4; i < K; i += 256 * 4) {
        float4 v = *(const float4*)(wr + i);
        m = fmaxf(m, fmaxf(fmaxf(fabsf(v.x), fabsf(v.y)),
                           fmaxf(fabsf(v.z), fabsf(v.w))));
    }
#pragma unroll
    for (int off = 1; off < 64; off <<= 1) m = fmaxf(m, __shfl_xor(m, off));
    __shared__ float wm[4];
    if ((t & 63) == 0) wm[t >> 6] = m;
    __syncthreads();
    m = fmaxf(fmaxf(wm[0], wm[1]), fmaxf(wm[2], wm[3]));
    const float scale = fmaxf(m / 127.0f, 1e-8f);
    for (int i = t * 4; i < K; i += 256 * 4) {
        float4 v = *(const float4*)(wr + i);
        short4 o;
        o.x = (short)f2bf(fq(v.x, scale));
        o.y = (short)f2bf(fq(v.y, scale));
        o.z = (short)f2bf(fq(v.z, scale));
        o.w = (short)f2bf(fq(v.w, scale));
        *(short4*)(wo + i) = o;
    }
}

// --------------------- GEMM: C[m][n] = sum_k A[m][k]*B[n][k] + bias[n] -----
// A: [M,K] bf16 (K-major), B: [N,K] bf16 (K-major) -> natural B^T GEMM.
// 128x128 tile, BK=32, 4 waves each own a 64x64 quadrant (4x4 16x16 frags).
// Staging: global_load_lds width=16; LDS image is tile rows packed [128][32],
// NO padding (wave-uniform-base + lane*16 constraint).
__global__ __launch_bounds__(256, 3) void gemm_bias_kernel(
        const short* __restrict__ A, const short* __restrict__ B,
        const float* __restrict__ bias, float* __restrict__ C,
        int M, int N, int K) {
    __shared__ __align__(16) short As[128 * 32];
    __shared__ __align__(16) short Bs[128 * 32];
    const int tid = threadIdx.x;
    const int wave = tid >> 6, lane = tid & 63;
    const int bm = blockIdx.y * 128, bn = blockIdx.x * 128;
    const int wm = (wave >> 1) * 64, wn = (wave & 1) * 64;

    f32x4 acc[4][4];
#pragma unroll
    for (int i = 0; i < 4; i++)
#pragma unroll
        for (int j = 0; j < 4; j++) acc[i][j] = (f32x4){0.f, 0.f, 0.f, 0.f};

    // staging addresses: chunk c = wave*2+j covers rows [c*16, c*16+16) of the
    // tile; lane covers row (lane>>2), cols (lane&3)*8 .. +8 (16 B).
    const size_t sK = (size_t)K;
    const short* Ag0 = A + (size_t)(bm + wave * 32 + (lane >> 2)) * sK + (lane & 3) * 8;
    const short* Ag1 = Ag0 + 16 * sK;
    const short* Bg0 = B + (size_t)(bn + wave * 32 + (lane >> 2)) * sK + (lane & 3) * 8;
    const short* Bg1 = Bg0 + 16 * sK;
    short* AsB0 = As + wave * 1024;        // wave-uniform LDS bases (shorts)
    short* AsB1 = As + wave * 1024 + 512;
    short* BsB0 = Bs + wave * 1024;
    short* BsB1 = Bs + wave * 1024 + 512;

    // fragment read bases: A[m=lane&15][k=(lane>>4)*8+j] (verified m120 layout)
    const int fr = lane & 15, fk = (lane >> 4) * 8;
    const short* aF = As + (wm + fr) * 32 + fk;
    const short* bF = Bs + (wn + fr) * 32 + fk;

    for (int k0 = 0; k0 < K; k0 += 32) {
        load_lds16(Ag0 + k0, AsB0);
        load_lds16(Ag1 + k0, AsB1);
        load_lds16(Bg0 + k0, BsB0);
        load_lds16(Bg1 + k0, BsB1);
        __syncthreads();  // drains vmcnt -> LDS tiles valid
        bf16x8 a[4], b[4];
#pragma unroll
        for (int i = 0; i < 4; i++) {
            a[i] = *(const bf16x8*)(aF + i * 512);  // +16 rows per frag
            b[i] = *(const bf16x8*)(bF + i * 512);
        }
#pragma unroll
        for (int mi = 0; mi < 4; mi++)
#pragma unroll
            for (int ni = 0; ni < 4; ni++)
                acc[mi][ni] = __builtin_amdgcn_mfma_f32_16x16x32_bf16(
                    a[mi], b[ni], acc[mi][ni], 0, 0, 0);
        __syncthreads();  // all frag reads done before next overwrite
    }

    // epilogue: C/D layout col=lane&15, row=(lane>>4)*4+reg (verified m89/m91)
    const int or0 = bm + wm + (lane >> 4) * 4;
    const int oc0 = bn + wn + (lane & 15);
    float bv[4];
#pragma unroll
    for (int ni = 0; ni < 4; ni++) bv[ni] = bias[oc0 + ni * 16];
#pragma unroll
    for (int mi = 0; mi < 4; mi++)
#pragma unroll
        for (int ni = 0; ni < 4; ni++)
#pragma unroll
            for (int r = 0; r < 4; r++)
                C[(size_t)(or0 + mi * 16 + r) * N + (oc0 + ni * 16)] =
                    acc[mi][ni][r] + bv[ni];
}

extern "C" void kernel_launch(void* const* d_in, const int* in_sizes, int n_in,
                              void* d_out, int out_size, void* d_ws, size_t ws_size,
                              hipStream_t stream) {
    const float* x    = (const float*)d_in[0];
    const float* w    = (const float*)d_in[1];
    const float* bias = (const float*)d_in[2];
    // d_in[3] is group_size (=128), hard-assumed below (8 lanes * 16 elems).

    const int out_f  = in_sizes[2];
    const int in_f   = in_sizes[1] / out_f;
    const int tokens = in_sizes[0] / in_f;

    short* xq = (short*)d_ws;                          // [tokens, in_f] bf16
    short* wq = xq + (size_t)tokens * in_f;            // [out_f, in_f] bf16
    float* out = (float*)d_out;

    act_quant_kernel<<<tokens, 256, 0, stream>>>(x, xq, in_f);
    wgt_quant_kernel<<<out_f, 256, 0, stream>>>(w, wq, in_f);

    dim3 grid(out_f / 128, tokens / 128);
    gemm_bias_kernel<<<grid, 256, 0, stream>>>(xq, wq, bias, out,
                                               tokens, out_f, in_f);
}

// Round 2
// 454.927 us; speedup vs baseline: 1.2367x; 1.2367x over previous
//
#include <hip/hip_runtime.h>
#include <stdint.h>

// ---------------------------------------------------------------------------
// QuantLinear via EXACT int8 path:
//   qx[t,k] int8, sx[t,g] (g=k/128) ; qw[o,k] int8, sw[o]
//   out[t,o] = sw[o] * sum_g sx[t,g] * (int dot over group g) + bias[o]
// GEMM: 128x128 tile, BK=128 (= one act-quant group per k-iter),
// mfma_i32_16x16x64_i8 chained x2 per group, per-group fp32 rescale.
// Staging: global_load_lds width=16 with global-side chunk XOR-swizzle so
// fragment ds_read_b128 hits 8 distinct bank-quads (2-way = free).
// ---------------------------------------------------------------------------

typedef __attribute__((ext_vector_type(4))) int   i32x4;
typedef __attribute__((ext_vector_type(4))) float f32x4;

static __device__ __forceinline__ void load_lds16(const void* g, void* l) {
    __builtin_amdgcn_global_load_lds(
        (const __attribute__((address_space(1))) void*)g,
        (__attribute__((address_space(3))) void*)l, 16, 0, 0);
}

static __device__ __forceinline__ int8_t q8(float v, float scale) {
    float q = rintf(v / scale);                 // half-even, matches np
    q = fminf(fmaxf(q, -128.0f), 127.0f);
    return (int8_t)(int)q;
}

// ---------------- act quant: per-group-128, coalesced ----------------------
// block = one token row (4096 elems). lane i owns float4 -> group of 128 =
// 32 consecutive lanes; shfl_xor(1,2,4,8,16) max-reduce. int8 out (uchar4).
__global__ __launch_bounds__(256) void act_quant_kernel(
        const float* __restrict__ x, int8_t* __restrict__ xq,
        float* __restrict__ sxT, int in_f, int M) {
    const int row = blockIdx.x, t = threadIdx.x;
    const float* xr = x + (size_t)row * in_f;
    int8_t* xo = xq + (size_t)row * in_f;
    for (int base = t * 4; base < in_f; base += 256 * 4) {
        float4 v = *(const float4*)(xr + base);
        float m = fmaxf(fmaxf(fabsf(v.x), fabsf(v.y)),
                        fmaxf(fabsf(v.z), fabsf(v.w)));
        m = fmaxf(m, __shfl_xor(m, 1));
        m = fmaxf(m, __shfl_xor(m, 2));
        m = fmaxf(m, __shfl_xor(m, 4));
        m = fmaxf(m, __shfl_xor(m, 8));
        m = fmaxf(m, __shfl_xor(m, 16));
        const float scale = fmaxf(m / 127.0f, 1e-8f);
        char4 o;
        o.x = q8(v.x, scale); o.y = q8(v.y, scale);
        o.z = q8(v.z, scale); o.w = q8(v.w, scale);
        *(char4*)(xo + base) = o;
        if ((t & 31) == 0)  // one scale per group; sxT layout [G, M]
            sxT[(size_t)(base >> 7) * M + row] = scale;
    }
}

// ---------------- weight quant: per-row, coalesced -------------------------
__global__ __launch_bounds__(256) void wgt_quant_kernel(
        const float* __restrict__ w, int8_t* __restrict__ wq,
        float* __restrict__ sw, int K) {
    const int row = blockIdx.x, t = threadIdx.x;
    const float* wr = w + (size_t)row * K;
    int8_t* wo = wq + (size_t)row * K;
    float m = 0.0f;
    for (int i = t * 4; i < K; i += 256 * 4) {
        float4 v = *(const float4*)(wr + i);
        m = fmaxf(m, fmaxf(fmaxf(fabsf(v.x), fabsf(v.y)),
                           fmaxf(fabsf(v.z), fabsf(v.w))));
    }
#pragma unroll
    for (int off = 1; off < 64; off <<= 1) m = fmaxf(m, __shfl_xor(m, off));
    __shared__ float wm[4];
    if ((t & 63) == 0) wm[t >> 6] = m;
    __syncthreads();
    m = fmaxf(fmaxf(wm[0], wm[1]), fmaxf(wm[2], wm[3]));
    const float scale = fmaxf(m / 127.0f, 1e-8f);
    if (t == 0) sw[row] = scale;
    for (int i = t * 4; i < K; i += 256 * 4) {
        float4 v = *(const float4*)(wr + i);
        char4 o;
        o.x = q8(v.x, scale); o.y = q8(v.y, scale);
        o.z = q8(v.z, scale); o.w = q8(v.w, scale);
        *(char4*)(wo + i) = o;
    }
}

// ---------------- int8 GEMM with per-group rescale -------------------------
// LDS image (A and B): row r (128 rows), 16B chunk C (8 chunks of K) stored at
// byte offset r*128 + (C ^ (r&7))*16  — produced by permuting which global
// chunk each staging lane fetches (DMA dest is fixed at base + lane*16).
__global__ __launch_bounds__(256, 2) void gemm_i8_kernel(
        const int8_t* __restrict__ A, const int8_t* __restrict__ B,
        const float* __restrict__ sxT, const float* __restrict__ sw,
        const float* __restrict__ bias, float* __restrict__ C,
        int M, int N, int K) {
    __shared__ __align__(16) int8_t As[128 * 128];
    __shared__ __align__(16) int8_t Bs[128 * 128];
    __shared__ float sxs[128];
    const int tid = threadIdx.x;
    const int wave = tid >> 6, lane = tid & 63;
    const int bm = blockIdx.y * 128, bn = blockIdx.x * 128;
    const int wm = (wave >> 1) * 64, wn = (wave & 1) * 64;

    f32x4 acc[4][4];
#pragma unroll
    for (int i = 0; i < 4; i++)
#pragma unroll
        for (int j = 0; j < 4; j++) acc[i][j] = (f32x4){0.f, 0.f, 0.f, 0.f};

    // staging: wave w, instr i covers rows i*32 + w*8 + (lane>>3);
    // lane fetches global chunk Cg = (lane&7) ^ ((lane>>3)&7) -> swizzled LDS.
    const int srow = wave * 8 + (lane >> 3);
    const int scol = (((lane & 7) ^ ((lane >> 3) & 7)) * 16);
    const size_t sK = (size_t)K;
    const int8_t* Ag = A + (size_t)(bm + srow) * sK + scol;
    const int8_t* Bg = B + (size_t)(bn + srow) * sK + scol;
    int8_t* AsW = As + (wave * 8) * 128;   // wave-uniform LDS bases
    int8_t* BsW = Bs + (wave * 8) * 128;

    // fragment read offsets: row = (wm|wn) + mi*16 + (lane&15),
    // chunk C = h*4 + (lane>>4), LDS pos = (C ^ (row&7)); row&7 == lane&7.
    const int fr = lane & 15, q = lane >> 4, r7 = lane & 7;
    const int gBase = bm;  // sx rows
    const int G = K >> 7;  (void)G;

    for (int k0 = 0; k0 < K; k0 += 128) {
#pragma unroll
        for (int i = 0; i < 4; i++) {
            load_lds16(Ag + k0 + (size_t)i * 32 * sK, AsW + i * 32 * 128);
            load_lds16(Bg + k0 + (size_t)i * 32 * sK, BsW + i * 32 * 128);
        }
        if (tid < 128) sxs[tid] = sxT[(size_t)(k0 >> 7) * M + gBase + tid];
        __syncthreads();

        i32x4 a[4][2], b[4][2];
        f32x4 sxv[4];
#pragma unroll
        for (int mi = 0; mi < 4; mi++) {
            const int arow = wm + mi * 16 + fr;
            const int brow = wn + mi * 16 + fr;
#pragma unroll
            for (int h = 0; h < 2; h++) {
                a[mi][h] = *(const i32x4*)(As + arow * 128 +
                                           ((h * 4 + q) ^ r7) * 16);
                b[mi][h] = *(const i32x4*)(Bs + brow * 128 +
                                           ((h * 4 + q) ^ r7) * 16);
            }
            sxv[mi] = *(const f32x4*)(sxs + wm + mi * 16 + q * 4);
        }
#pragma unroll
        for (int mi = 0; mi < 4; mi++)
#pragma unroll
            for (int ni = 0; ni < 4; ni++) {
                i32x4 iacc = __builtin_amdgcn_mfma_i32_16x16x64_i8(
                    a[mi][0], b[ni][0], (i32x4){0, 0, 0, 0}, 0, 0, 0);
                iacc = __builtin_amdgcn_mfma_i32_16x16x64_i8(
                    a[mi][1], b[ni][1], iacc, 0, 0, 0);
#pragma unroll
                for (int r = 0; r < 4; r++)
                    acc[mi][ni][r] += (float)iacc[r] * sxv[mi][r];
            }
        __syncthreads();
    }

    // epilogue: C/D layout col=lane&15, row=(lane>>4)*4+reg; fold sw + bias
    const int or0 = bm + wm + q * 4;
    const int oc0 = bn + wn + fr;
    float swv[4], bv[4];
#pragma unroll
    for (int ni = 0; ni < 4; ni++) {
        swv[ni] = sw[oc0 + ni * 16];
        bv[ni] = bias[oc0 + ni * 16];
    }
#pragma unroll
    for (int mi = 0; mi < 4; mi++)
#pragma unroll
        for (int ni = 0; ni < 4; ni++)
#pragma unroll
            for (int r = 0; r < 4; r++)
                C[(size_t)(or0 + mi * 16 + r) * N + (oc0 + ni * 16)] =
                    acc[mi][ni][r] * swv[ni] + bv[ni];
}

extern "C" void kernel_launch(void* const* d_in, const int* in_sizes, int n_in,
                              void* d_out, int out_size, void* d_ws, size_t ws_size,
                              hipStream_t stream) {
    const float* x    = (const float*)d_in[0];
    const float* w    = (const float*)d_in[1];
    const float* bias = (const float*)d_in[2];
    // d_in[3] = group_size (128) — hard-assumed (32 lanes x float4 per group).

    const int out_f  = in_sizes[2];
    const int in_f   = in_sizes[1] / out_f;
    const int tokens = in_sizes[0] / in_f;
    const int G = in_f / 128;

    int8_t* xq  = (int8_t*)d_ws;                         // [M,K] int8
    int8_t* wq  = xq + (size_t)tokens * in_f;            // [N,K] int8
    float*  sxT = (float*)(wq + (size_t)out_f * in_f);   // [G,M] fp32
    float*  sw  = sxT + (size_t)G * tokens;              // [N]  fp32
    float*  out = (float*)d_out;

    act_quant_kernel<<<tokens, 256, 0, stream>>>(x, xq, sxT, in_f, tokens);
    wgt_quant_kernel<<<out_f, 256, 0, stream>>>(w, wq, sw, in_f);

    dim3 grid(out_f / 128, tokens / 128);
    gemm_i8_kernel<<<grid, 256, 0, stream>>>(xq, wq, sxT, sw, bias, out,
                                             tokens, out_f, in_f);
}

// Round 3
// 445.133 us; speedup vs baseline: 1.2639x; 1.0220x over previous
//
#include <hip/hip_runtime.h>
#include <stdint.h>

// ---------------------------------------------------------------------------
// QuantLinear via EXACT int8 path:
//   qx[t,k] int8, sx[t,g] (g=k/128) ; qw[o,k] int8, sw[o]
//   out[t,o] = sw[o] * sum_g sx[t,g] * (int dot over group g) + bias[o]
// R3: fused single-dispatch quant (wgt single-HBM-pass), GEMM drops sxs LDS
// (per-group scales read from global, L2-hot) -> 32 KB LDS, 5 blocks/CU.
// ---------------------------------------------------------------------------

typedef __attribute__((ext_vector_type(4))) int   i32x4;
typedef __attribute__((ext_vector_type(4))) float f32x4;

static __device__ __forceinline__ void load_lds16(const void* g, void* l) {
    __builtin_amdgcn_global_load_lds(
        (const __attribute__((address_space(1))) void*)g,
        (__attribute__((address_space(3))) void*)l, 16, 0, 0);
}

static __device__ __forceinline__ int8_t q8(float v, float scale) {
    float q = rintf(v / scale);                 // half-even, matches np
    q = fminf(fmaxf(q, -128.0f), 127.0f);
    return (int8_t)(int)q;
}

// ---------------- fused quant: act rows then weight rows -------------------
// block b < M  : act row b, per-group-128 (32 lanes x float4), shfl-reduce
// block b >= M : weight row b-M, single HBM pass (row lives in 16 VGPRs)
__global__ __launch_bounds__(256) void quant_fused_kernel(
        const float* __restrict__ x, int8_t* __restrict__ xq,
        float* __restrict__ sxT,
        const float* __restrict__ w, int8_t* __restrict__ wq,
        float* __restrict__ sw, int in_f, int M) {
    const int b = blockIdx.x, t = threadIdx.x;
    if (b < M) {
        const int row = b;
        const float* xr = x + (size_t)row * in_f;
        int8_t* xo = xq + (size_t)row * in_f;
        for (int base = t * 4; base < in_f; base += 256 * 4) {
            float4 v = *(const float4*)(xr + base);
            float m = fmaxf(fmaxf(fabsf(v.x), fabsf(v.y)),
                            fmaxf(fabsf(v.z), fabsf(v.w)));
            m = fmaxf(m, __shfl_xor(m, 1));
            m = fmaxf(m, __shfl_xor(m, 2));
            m = fmaxf(m, __shfl_xor(m, 4));
            m = fmaxf(m, __shfl_xor(m, 8));
            m = fmaxf(m, __shfl_xor(m, 16));
            const float scale = fmaxf(m / 127.0f, 1e-8f);
            char4 o;
            o.x = q8(v.x, scale); o.y = q8(v.y, scale);
            o.z = q8(v.z, scale); o.w = q8(v.w, scale);
            *(char4*)(xo + base) = o;
            if ((t & 31) == 0)  // sxT layout [G, M]
                sxT[(size_t)(base >> 7) * M + row] = scale;
        }
    } else {
        const int row = b - M;
        const float* wr = w + (size_t)row * in_f;
        int8_t* wo = wq + (size_t)row * in_f;
        // K=4096: 16 floats/thread in regs -> one HBM pass
        float4 v[4];
        float m = 0.0f;
#pragma unroll
        for (int i = 0; i < 4; i++) {
            v[i] = *(const float4*)(wr + t * 4 + i * 1024);
            m = fmaxf(m, fmaxf(fmaxf(fabsf(v[i].x), fabsf(v[i].y)),
                               fmaxf(fabsf(v[i].z), fabsf(v[i].w))));
        }
#pragma unroll
        for (int off = 1; off < 64; off <<= 1)
            m = fmaxf(m, __shfl_xor(m, off));
        __shared__ float wm[4];
        if ((t & 63) == 0) wm[t >> 6] = m;
        __syncthreads();
        m = fmaxf(fmaxf(wm[0], wm[1]), fmaxf(wm[2], wm[3]));
        const float scale = fmaxf(m / 127.0f, 1e-8f);
        if (t == 0) sw[row] = scale;
#pragma unroll
        for (int i = 0; i < 4; i++) {
            char4 o;
            o.x = q8(v[i].x, scale); o.y = q8(v[i].y, scale);
            o.z = q8(v[i].z, scale); o.w = q8(v[i].w, scale);
            *(char4*)(wo + t * 4 + i * 1024) = o;
        }
    }
}

// ---------------- int8 GEMM with per-group rescale -------------------------
// LDS image (A and B): row r (128 rows), 16B chunk C (8 chunks of K) stored at
// byte offset r*128 + (C ^ (r&7))*16  — produced by permuting which global
// chunk each staging lane fetches (DMA dest is fixed at base + lane*16).
// Act scales sxT[g, m] read straight from global (L2-hot) per iteration.
__global__ __launch_bounds__(256, 2) void gemm_i8_kernel(
        const int8_t* __restrict__ A, const int8_t* __restrict__ B,
        const float* __restrict__ sxT, const float* __restrict__ sw,
        const float* __restrict__ bias, float* __restrict__ C,
        int M, int N, int K) {
    __shared__ __align__(16) int8_t As[128 * 128];
    __shared__ __align__(16) int8_t Bs[128 * 128];
    const int tid = threadIdx.x;
    const int wave = tid >> 6, lane = tid & 63;
    const int bm = blockIdx.y * 128, bn = blockIdx.x * 128;
    const int wm = (wave >> 1) * 64, wn = (wave & 1) * 64;

    f32x4 acc[4][4];
#pragma unroll
    for (int i = 0; i < 4; i++)
#pragma unroll
        for (int j = 0; j < 4; j++) acc[i][j] = (f32x4){0.f, 0.f, 0.f, 0.f};

    // staging: wave w, instr i covers rows i*32 + w*8 + (lane>>3);
    // lane fetches global chunk Cg = (lane&7) ^ ((lane>>3)&7) -> swizzled LDS.
    const int srow = wave * 8 + (lane >> 3);
    const int scol = (((lane & 7) ^ ((lane >> 3) & 7)) * 16);
    const size_t sK = (size_t)K;
    const int8_t* Ag = A + (size_t)(bm + srow) * sK + scol;
    const int8_t* Bg = B + (size_t)(bn + srow) * sK + scol;
    int8_t* AsW = As + (wave * 8) * 128;   // wave-uniform LDS bases
    int8_t* BsW = Bs + (wave * 8) * 128;

    // fragment reads: row = (wm|wn) + mi*16 + (lane&15),
    // chunk C = h*4 + (lane>>4), LDS pos = (C ^ (row&7)); row&7 == lane&7.
    const int fr = lane & 15, q = lane >> 4, r7 = lane & 7;
    const float* sxg = sxT + bm + wm + q * 4;  // + g*M per iter

    for (int k0 = 0; k0 < K; k0 += 128) {
#pragma unroll
        for (int i = 0; i < 4; i++) {
            load_lds16(Ag + k0 + (size_t)i * 32 * sK, AsW + i * 32 * 128);
            load_lds16(Bg + k0 + (size_t)i * 32 * sK, BsW + i * 32 * 128);
        }
        // per-group act scales for this wave's 64 rows (L2/L1-hot)
        f32x4 sxv[4];
#pragma unroll
        for (int mi = 0; mi < 4; mi++)
            sxv[mi] = *(const f32x4*)(sxg + (size_t)(k0 >> 7) * M + mi * 16);
        __syncthreads();

        i32x4 a[4][2], b[4][2];
#pragma unroll
        for (int mi = 0; mi < 4; mi++) {
            const int arow = wm + mi * 16 + fr;
            const int brow = wn + mi * 16 + fr;
#pragma unroll
            for (int h = 0; h < 2; h++) {
                a[mi][h] = *(const i32x4*)(As + arow * 128 +
                                           ((h * 4 + q) ^ r7) * 16);
                b[mi][h] = *(const i32x4*)(Bs + brow * 128 +
                                           ((h * 4 + q) ^ r7) * 16);
            }
        }
#pragma unroll
        for (int mi = 0; mi < 4; mi++)
#pragma unroll
            for (int ni = 0; ni < 4; ni++) {
                i32x4 iacc = __builtin_amdgcn_mfma_i32_16x16x64_i8(
                    a[mi][0], b[ni][0], (i32x4){0, 0, 0, 0}, 0, 0, 0);
                iacc = __builtin_amdgcn_mfma_i32_16x16x64_i8(
                    a[mi][1], b[ni][1], iacc, 0, 0, 0);
#pragma unroll
                for (int r = 0; r < 4; r++)
                    acc[mi][ni][r] += (float)iacc[r] * sxv[mi][r];
            }
        __syncthreads();
    }

    // epilogue: C/D layout col=lane&15, row=(lane>>4)*4+reg; fold sw + bias
    const int or0 = bm + wm + q * 4;
    const int oc0 = bn + wn + fr;
    float swv[4], bv[4];
#pragma unroll
    for (int ni = 0; ni < 4; ni++) {
        swv[ni] = sw[oc0 + ni * 16];
        bv[ni] = bias[oc0 + ni * 16];
    }
#pragma unroll
    for (int mi = 0; mi < 4; mi++)
#pragma unroll
        for (int ni = 0; ni < 4; ni++)
#pragma unroll
            for (int r = 0; r < 4; r++)
                C[(size_t)(or0 + mi * 16 + r) * N + (oc0 + ni * 16)] =
                    acc[mi][ni][r] * swv[ni] + bv[ni];
}

extern "C" void kernel_launch(void* const* d_in, const int* in_sizes, int n_in,
                              void* d_out, int out_size, void* d_ws, size_t ws_size,
                              hipStream_t stream) {
    const float* x    = (const float*)d_in[0];
    const float* w    = (const float*)d_in[1];
    const float* bias = (const float*)d_in[2];
    // d_in[3] = group_size (128) — hard-assumed (32 lanes x float4 per group).

    const int out_f  = in_sizes[2];
    const int in_f   = in_sizes[1] / out_f;   // 4096 (wgt path assumes this)
    const int tokens = in_sizes[0] / in_f;
    const int G = in_f / 128;

    int8_t* xq  = (int8_t*)d_ws;                         // [M,K] int8
    int8_t* wq  = xq + (size_t)tokens * in_f;            // [N,K] int8
    float*  sxT = (float*)(wq + (size_t)out_f * in_f);   // [G,M] fp32
    float*  sw  = sxT + (size_t)G * tokens;              // [N]  fp32
    float*  out = (float*)d_out;

    quant_fused_kernel<<<tokens + out_f, 256, 0, stream>>>(
        x, xq, sxT, w, wq, sw, in_f, tokens);

    dim3 grid(out_f / 128, tokens / 128);
    gemm_i8_kernel<<<grid, 256, 0, stream>>>(xq, wq, sxT, sw, bias, out,
                                             tokens, out_f, in_f);
}